// Round 2
// baseline (179.014 us; speedup 1.0000x reference)
//
#include <hip/hip_runtime.h>

#define IMH 384
#define IMW 384
#define OH 378
#define OW 378
#define NB 64
#define SROWS 18
#define INROWS 24          // SROWS + 6
#define NSTRIP 21          // 21*18 = 378 exactly
#define NSEG 15            // ceil(378/26) column segments per strip
#define BLOCK 256          // 4 waves = 16 DPP groups of 16 lanes
#define GSTRIDE 26         // output cols per group (13 lanes x 2 cols)
#define NTASK (NB * NSTRIP * NSEG)   // 20160 group-tasks
#define NBLOCKS (NTASK / 16)         // 1260 blocks, no dead groups

// Round 11: R10 (waves_per_eu 6,6 + 3-DPP + spread atomics) = 33.06us.
// Still ~2x above max(HBM ~12us, VALU ~6.5us). Three fixes:
//  1. Dead-group elimination: 16 groups x 26 = 416 cols for 378 needed ->
//     group 15 was 100% waste (6.25% of all work). Now (b,strip,seg) is
//     linearized into 20160 group-tasks, 16 per block, 1260 blocks exactly.
//     Groups in a block may span batches; reduction is per-group: 16-lane
//     shuffle -> one atomicAdd into acc[b] (315 adds/slot).
//  2. Fused finalize: last-block-done ticket at acc[64]; the last block
//     coherent-reads acc[0..63] (atomic-add 0) and writes out. Saves the
//     finalize dispatch + inter-kernel gap in the graph.
//  3. Depth-3 load pipeline: re-poisoned inputs stream from HBM (~900cy);
//     depth-2 gave ~750cy of hiding at 6 waves/EU. +4 VGPRs, budget fine.

template <int CTRL>
__device__ __forceinline__ float dpp_sh(float v) {
    return __int_as_float(__builtin_amdgcn_update_dpp(
        0, __float_as_int(v), CTRL, 0xf, 0xf, true));
}

__device__ __forceinline__ float2 f2add(float2 a, float2 b) { return make_float2(a.x + b.x, a.y + b.y); }
__device__ __forceinline__ float2 f2sub(float2 a, float2 b) { return make_float2(a.x - b.x, a.y - b.y); }
__device__ __forceinline__ float2 f2mul(float2 a, float2 b) { return make_float2(a.x * b.x, a.y * b.y); }
__device__ __forceinline__ float2 f2fma(float2 a, float2 b, float2 c) {
    return make_float2(fmaf(a.x, b.x, c.x), fmaf(a.y, b.y, c.y));
}
__device__ __forceinline__ float2 f2fnma(float2 a, float2 b, float2 c) {  // c - a*b
    return make_float2(fmaf(-a.x, b.x, c.x), fmaf(-a.y, b.y, c.y));
}
__device__ __forceinline__ float2 f2fms(float2 a, float s, float2 c) {    // a*s - c
    return make_float2(fmaf(a.x, s, -c.x), fmaf(a.y, s, -c.y));
}
__device__ __forceinline__ float2 f2s(float s) { return make_float2(s, s); }

__global__ __launch_bounds__(BLOCK)
__attribute__((amdgpu_waves_per_eu(6, 6)))
void ssim_kernel(
    const float* __restrict__ X, const float* __restrict__ Y,
    const float* __restrict__ data_range, float* __restrict__ acc,
    float* __restrict__ out)
{
    const int tid = threadIdx.x;
    const int g   = tid >> 4;                 // DPP group 0..15
    const int j   = tid & 15;                 // lane within group

    // ---- linearized task decode: t -> (b, strip, seg) ----
    const int t     = blockIdx.x * (BLOCK / 16) + g;
    const int b     = t / (NSTRIP * NSEG);          // /315 (magic mul)
    const int r2    = t - b * (NSTRIP * NSEG);
    const int strip = r2 / NSEG;                    // /15
    const int seg   = r2 - strip * NSEG;
    const int y0    = strip * SROWS;

    const float* __restrict__ Xb = X + b * (IMH * IMW);
    const float* __restrict__ Yb = Y + b * (IMH * IMW);

    const int ce  = seg * GSTRIDE + 2 * j;    // lane's even column (global)
    const int cin = min(ce, IMW - 2);         // clamped, even -> 8B aligned
    const float2 vmask = make_float2(
        ((j <= 12) && (ce     < OW)) ? 1.f : 0.f,
        ((j <= 12) && (ce + 1 < OW)) ? 1.f : 0.f);

    const float L     = data_range[b];
    const float C1    = (0.01f * L) * (0.01f * L);
    const float C2    = (0.03f * L) * (0.03f * L);
    const float inv49 = 1.0f / 49.0f;
    const float covn  = 49.0f / 48.0f;

    // per-lane raw history of its 2 columns + running vertical sums
    float2 xh[7], yh[7];
    #pragma unroll
    for (int k = 0; k < 7; ++k) { xh[k] = f2s(0.f); yh[k] = f2s(0.f); }
    float2 V0 = f2s(0.f), V1 = f2s(0.f), V2 = f2s(0.f),
           V3 = f2s(0.f), V4 = f2s(0.f);
    float2 ls2 = f2s(0.f);

    // depth-3 explicit pipeline: rows r+1, r+2, r+3 in flight
    float2 px[3], py[3];
    #pragma unroll
    for (int k = 0; k < 3; ++k) {
        const int rk = min(y0 + k, IMH - 1);
        px[k] = *(const float2*)(Xb + rk * IMW + cin);
        py[k] = *(const float2*)(Yb + rk * IMW + cin);
    }

    #pragma unroll
    for (int r = 0; r < INROWS; ++r) {
        const int slot = r % 3;                        // static after unroll
        const float2 x = px[slot], y = py[slot];
        if (r + 3 < INROWS) {                          // refill consumed slot
            const int ri = min(y0 + r + 3, IMH - 1);   // uniform row clamp
            px[slot] = *(const float2*)(Xb + ri * IMW + cin);
            py[slot] = *(const float2*)(Yb + ri * IMW + cin);
        }

        // vertical 7-row slide on both columns (pk-f32 eligible)
        const int ks = r % 7;                          // static after unroll
        const float2 xo = xh[ks], yo = yh[ks];
        V0 = f2add(V0, f2sub(x, xo));
        V1 = f2add(V1, f2sub(y, yo));
        V2 = f2fma(x, x, V2);  V2 = f2fnma(xo, xo, V2);
        V3 = f2fma(x, y, V3);  V3 = f2fnma(xo, yo, V3);
        V4 = f2fma(y, y, V4);  V4 = f2fnma(yo, yo, V4);
        xh[ks] = x; yh[ks] = y;

        if (r >= 6) {   // output row o = y0+r-6; tiling guarantees o < OH
            // horizontal 7-window sums for even+odd output cols, 3 DPP each:
            //   pp(l) = e(l)+o(l)
            //   C(l)  = pp(l)+pp(l+1)+pp(l+2)+pp(l+3)   (2 shifted adds)
            //   Se(l) = cols 2l..2l+6   = C(l) - o(l+3)
            //   So(l) = cols 2l+1..2l+7 = C(l) - e(l)
            const float2 Vv[5] = {V0, V1, V2, V3, V4};
            float Se[5], So[5];
            #pragma unroll
            for (int p = 0; p < 5; ++p) {
                const float e  = Vv[p].x;
                const float o  = Vv[p].y;
                const float pp = e + o;
                float B = pp + dpp_sh<0x101>(pp);      // pp(l)+pp(l+1)
                float C = B + dpp_sh<0x102>(B);        // pp(l..l+3)
                Se[p] = C - dpp_sh<0x103>(o);          // cols 2l..2l+6
                So[p] = C - e;                         // cols 2l+1..2l+7
            }
            const float2 S0 = make_float2(Se[0], So[0]);
            const float2 S1 = make_float2(Se[1], So[1]);
            const float2 S2 = make_float2(Se[2], So[2]);
            const float2 S3 = make_float2(Se[3], So[3]);
            const float2 S4 = make_float2(Se[4], So[4]);

            float2 ux   = f2mul(S0, f2s(inv49));
            float2 uy   = f2mul(S1, f2s(inv49));
            float2 uxux = f2mul(ux, ux);
            float2 uyuy = f2mul(uy, uy);
            float2 uxuy = f2mul(ux, uy);
            float2 vx   = f2mul(f2fms(S2, inv49, uxux), f2s(covn));
            float2 vy   = f2mul(f2fms(S4, inv49, uyuy), f2s(covn));
            float2 vxy  = f2mul(f2fms(S3, inv49, uxuy), f2s(covn));
            float2 N1   = f2fma(f2s(2.f), uxuy, f2s(C1));
            float2 N2   = f2fma(f2s(2.f), vxy, f2s(C2));
            float2 D1   = f2add(f2add(uxux, uyuy), f2s(C1));
            float2 D2   = f2add(f2add(vx, vy), f2s(C2));
            float2 num  = f2mul(N1, N2);
            float2 den  = f2mul(D1, D2);
            // one rcp for both columns: se = nx*dy/(dx*dy), so = ny*dx/(dx*dy)
            const float rdd = __builtin_amdgcn_rcpf(den.x * den.y);
            float2 s2 = make_float2(num.x * den.y * rdd,
                                    num.y * den.x * rdd);
            ls2 = f2fma(s2, vmask, ls2);
        }
    }

    float lsum = ls2.x + ls2.y;

    // ---- per-group reduction (groups may have different b) ----
    #pragma unroll
    for (int off = 8; off > 0; off >>= 1)
        lsum += __shfl_down(lsum, off, 16);
    if (j == 0) atomicAdd(acc + b, lsum);     // 315 adds per slot

    // ---- fused finalize: last-block-done ----
    __shared__ int lastblk;
    __syncthreads();                          // drains this block's atomics
    if (tid == 0) {
        __threadfence();
        lastblk = (atomicAdd((int*)(acc + NB), 1) == NBLOCKS - 1) ? 1 : 0;
    }
    __syncthreads();
    if (lastblk && tid < NB) {
        float v = atomicAdd(acc + tid, 0.0f); // coherent read of slot
        #pragma unroll
        for (int off = 32; off > 0; off >>= 1)
            v += __shfl_down(v, off, 64);
        if (tid == 0)
            out[0] = 1.0f - v * (1.0f / (float)(NB * OH * OW));
    }
}

extern "C" void kernel_launch(void* const* d_in, const int* in_sizes, int n_in,
                              void* d_out, int out_size, void* d_ws, size_t ws_size,
                              hipStream_t stream) {
    const float* X  = (const float*)d_in[0];
    const float* Y  = (const float*)d_in[1];
    const float* dr = (const float*)d_in[2];
    float* out = (float*)d_out;
    float* acc = (float*)d_ws;

    hipMemsetAsync(acc, 0, (NB + 1) * sizeof(float), stream);  // slots + ticket

    dim3 grid(NBLOCKS);         // 1260 blocks, 16 live group-tasks each
    dim3 block(BLOCK);          // 256 threads = 4 waves
    ssim_kernel<<<grid, block, 0, stream>>>(X, Y, dr, acc, out);
}

// Round 3
// 32.509 us; speedup vs baseline: 5.5065x; 5.5065x over previous
//
#include <hip/hip_runtime.h>

#define IMH 384
#define IMW 384
#define OH 378
#define OW 378
#define NB 64
#define SROWS 9
#define INROWS 15          // SROWS + 6
#define NSTRIP 42          // 42*9 = 378 exactly
#define NSEG 15            // ceil(378/26) column segments per strip
#define BLOCK 256          // 4 waves = 16 DPP groups of 16 lanes
#define GSTRIDE 26         // output cols per group (13 lanes x 2 cols)
#define TPB (NSTRIP * NSEG)          // 630 tasks per batch
#define NTASK (NB * TPB)             // 40320 group-tasks
#define NBLOCKS (NTASK / 16)         // 2520 blocks, no dead groups
#define ACCSTRIDE 32                 // one 128B line per batch slot

// Round 12: R11's 179us regression was the per-group atomic: 20160 f32 RMWs
// into a 256B region (WRITE_SIZE 668KB = 20160x32B sector writebacks), each
// block then draining vmcnt at __syncthreads -> whole device parked
// (VALUBusy 8.5%). Fixes:
//  1. Per-block reduction restored: a block's 16 linear tasks span <=2
//     batches, so LDS (sum,b) per group -> 16-lane masked shuffle reduce ->
//     <=2 atomics/block into line-padded acc slots (128B apart).
//  2. Fused-finalize ticket (1260 same-address atomics) reverted -> separate
//     64-thread finalize kernel (R10-proven).
//  3. Depth-2 pipeline restored (R11's depth-3 pushed allocator to 40 VGPR
//     remat mode).
//  4. Kept: dead-group-free linearized decode (R11's one real win).
//  5. New: SROWS 18->9. R10/R11 profiles show ~90% per-wave stall with the
//     grid (4.9 waves/EU), not VGPRs, capping occupancy. 2520 blocks = 10080
//     waves doubles memory-level parallelism for +25% halo work.

template <int CTRL>
__device__ __forceinline__ float dpp_sh(float v) {
    return __int_as_float(__builtin_amdgcn_update_dpp(
        0, __float_as_int(v), CTRL, 0xf, 0xf, true));
}

__device__ __forceinline__ float2 f2add(float2 a, float2 b) { return make_float2(a.x + b.x, a.y + b.y); }
__device__ __forceinline__ float2 f2sub(float2 a, float2 b) { return make_float2(a.x - b.x, a.y - b.y); }
__device__ __forceinline__ float2 f2mul(float2 a, float2 b) { return make_float2(a.x * b.x, a.y * b.y); }
__device__ __forceinline__ float2 f2fma(float2 a, float2 b, float2 c) {
    return make_float2(fmaf(a.x, b.x, c.x), fmaf(a.y, b.y, c.y));
}
__device__ __forceinline__ float2 f2fnma(float2 a, float2 b, float2 c) {  // c - a*b
    return make_float2(fmaf(-a.x, b.x, c.x), fmaf(-a.y, b.y, c.y));
}
__device__ __forceinline__ float2 f2fms(float2 a, float s, float2 c) {    // a*s - c
    return make_float2(fmaf(a.x, s, -c.x), fmaf(a.y, s, -c.y));
}
__device__ __forceinline__ float2 f2s(float s) { return make_float2(s, s); }

__global__ __launch_bounds__(BLOCK)
__attribute__((amdgpu_waves_per_eu(6, 6)))
void ssim_kernel(
    const float* __restrict__ X, const float* __restrict__ Y,
    const float* __restrict__ data_range, float* __restrict__ acc)
{
    const int tid = threadIdx.x;
    const int g   = tid >> 4;                 // DPP group 0..15
    const int j   = tid & 15;                 // lane within group

    // ---- linearized task decode: t -> (b, strip, seg) ----
    const int t     = blockIdx.x * (BLOCK / 16) + g;
    const int b     = t / TPB;                      // /630 (magic mul)
    const int r2    = t - b * TPB;
    const int strip = r2 / NSEG;                    // /15
    const int seg   = r2 - strip * NSEG;
    const int y0    = strip * SROWS;

    const float* __restrict__ Xb = X + b * (IMH * IMW);
    const float* __restrict__ Yb = Y + b * (IMH * IMW);

    const int ce  = seg * GSTRIDE + 2 * j;    // lane's even column (global)
    const int cin = min(ce, IMW - 2);         // clamped, even -> 8B aligned
    const float2 vmask = make_float2(
        ((j <= 12) && (ce     < OW)) ? 1.f : 0.f,
        ((j <= 12) && (ce + 1 < OW)) ? 1.f : 0.f);

    const float L     = data_range[b];
    const float C1    = (0.01f * L) * (0.01f * L);
    const float C2    = (0.03f * L) * (0.03f * L);
    const float inv49 = 1.0f / 49.0f;
    const float covn  = 49.0f / 48.0f;

    // per-lane raw history of its 2 columns + running vertical sums
    float2 xh[7], yh[7];
    #pragma unroll
    for (int k = 0; k < 7; ++k) { xh[k] = f2s(0.f); yh[k] = f2s(0.f); }
    float2 V0 = f2s(0.f), V1 = f2s(0.f), V2 = f2s(0.f),
           V3 = f2s(0.f), V4 = f2s(0.f);
    float2 ls2 = f2s(0.f);

    // depth-2 explicit pipeline: rows r+1 and r+2 in flight
    float2 px[2], py[2];
    {
        const int r0 = min(y0,     IMH - 1);
        const int r1 = min(y0 + 1, IMH - 1);
        px[0] = *(const float2*)(Xb + r0 * IMW + cin);
        py[0] = *(const float2*)(Yb + r0 * IMW + cin);
        px[1] = *(const float2*)(Xb + r1 * IMW + cin);
        py[1] = *(const float2*)(Yb + r1 * IMW + cin);
    }

    #pragma unroll
    for (int r = 0; r < INROWS; ++r) {
        const int slot = r & 1;                        // static after unroll
        const float2 x = px[slot], y = py[slot];
        if (r + 2 < INROWS) {                          // refill consumed slot
            const int ri = min(y0 + r + 2, IMH - 1);   // uniform row clamp
            px[slot] = *(const float2*)(Xb + ri * IMW + cin);
            py[slot] = *(const float2*)(Yb + ri * IMW + cin);
        }

        // vertical 7-row slide on both columns (pk-f32 eligible)
        const int ks = r % 7;                          // static after unroll
        const float2 xo = xh[ks], yo = yh[ks];
        V0 = f2add(V0, f2sub(x, xo));
        V1 = f2add(V1, f2sub(y, yo));
        V2 = f2fma(x, x, V2);  V2 = f2fnma(xo, xo, V2);
        V3 = f2fma(x, y, V3);  V3 = f2fnma(xo, yo, V3);
        V4 = f2fma(y, y, V4);  V4 = f2fnma(yo, yo, V4);
        xh[ks] = x; yh[ks] = y;

        if (r >= 6) {   // output row o = y0+r-6; tiling guarantees o < OH
            // horizontal 7-window sums for even+odd output cols, 3 DPP each:
            //   pp(l) = e(l)+o(l)
            //   C(l)  = pp(l)+pp(l+1)+pp(l+2)+pp(l+3)   (2 shifted adds)
            //   Se(l) = cols 2l..2l+6   = C(l) - o(l+3)
            //   So(l) = cols 2l+1..2l+7 = C(l) - e(l)
            const float2 Vv[5] = {V0, V1, V2, V3, V4};
            float Se[5], So[5];
            #pragma unroll
            for (int p = 0; p < 5; ++p) {
                const float e  = Vv[p].x;
                const float o  = Vv[p].y;
                const float pp = e + o;
                float B = pp + dpp_sh<0x101>(pp);      // pp(l)+pp(l+1)
                float C = B + dpp_sh<0x102>(B);        // pp(l..l+3)
                Se[p] = C - dpp_sh<0x103>(o);          // cols 2l..2l+6
                So[p] = C - e;                         // cols 2l+1..2l+7
            }
            const float2 S0 = make_float2(Se[0], So[0]);
            const float2 S1 = make_float2(Se[1], So[1]);
            const float2 S2 = make_float2(Se[2], So[2]);
            const float2 S3 = make_float2(Se[3], So[3]);
            const float2 S4 = make_float2(Se[4], So[4]);

            float2 ux   = f2mul(S0, f2s(inv49));
            float2 uy   = f2mul(S1, f2s(inv49));
            float2 uxux = f2mul(ux, ux);
            float2 uyuy = f2mul(uy, uy);
            float2 uxuy = f2mul(ux, uy);
            float2 vx   = f2mul(f2fms(S2, inv49, uxux), f2s(covn));
            float2 vy   = f2mul(f2fms(S4, inv49, uyuy), f2s(covn));
            float2 vxy  = f2mul(f2fms(S3, inv49, uxuy), f2s(covn));
            float2 N1   = f2fma(f2s(2.f), uxuy, f2s(C1));
            float2 N2   = f2fma(f2s(2.f), vxy, f2s(C2));
            float2 D1   = f2add(f2add(uxux, uyuy), f2s(C1));
            float2 D2   = f2add(f2add(vx, vy), f2s(C2));
            float2 num  = f2mul(N1, N2);
            float2 den  = f2mul(D1, D2);
            // one rcp for both columns: se = nx*dy/(dx*dy), so = ny*dx/(dx*dy)
            const float rdd = __builtin_amdgcn_rcpf(den.x * den.y);
            float2 s2 = make_float2(num.x * den.y * rdd,
                                    num.y * den.x * rdd);
            ls2 = f2fma(s2, vmask, ls2);
        }
    }

    float lsum = ls2.x + ls2.y;

    // ---- per-group 16-lane reduce, then per-block <=2 atomics ----
    #pragma unroll
    for (int off = 8; off > 0; off >>= 1)
        lsum += __shfl_down(lsum, off, 16);

    __shared__ float gsum[16];
    __shared__ int   gb[16];
    if (j == 0) { gsum[g] = lsum; gb[g] = b; }
    __syncthreads();
    if (tid < 16) {
        const float v  = gsum[tid];
        const int   bv = gb[tid];
        const int   b0 = gb[0];
        const int   b1 = gb[15];
        float m0 = (bv == b0) ? v : 0.f;
        float m1 = (bv != b0) ? v : 0.f;
        #pragma unroll
        for (int off = 8; off > 0; off >>= 1) {
            m0 += __shfl_down(m0, off, 16);
            m1 += __shfl_down(m1, off, 16);
        }
        if (tid == 0) {
            atomicAdd(acc + b0 * ACCSTRIDE, m0);
            if (b1 != b0) atomicAdd(acc + b1 * ACCSTRIDE, m1);
        }
    }
}

__global__ void finalize_kernel(const float* __restrict__ acc,
                                float* __restrict__ out)
{
    float v = acc[threadIdx.x * ACCSTRIDE];   // 64 threads, one slot each
    #pragma unroll
    for (int off = 32; off > 0; off >>= 1)
        v += __shfl_down(v, off, 64);
    if (threadIdx.x == 0)
        out[0] = 1.0f - v * (1.0f / (float)(NB * OH * OW));
}

extern "C" void kernel_launch(void* const* d_in, const int* in_sizes, int n_in,
                              void* d_out, int out_size, void* d_ws, size_t ws_size,
                              hipStream_t stream) {
    const float* X  = (const float*)d_in[0];
    const float* Y  = (const float*)d_in[1];
    const float* dr = (const float*)d_in[2];
    float* out = (float*)d_out;
    float* acc = (float*)d_ws;

    hipMemsetAsync(acc, 0, NB * ACCSTRIDE * sizeof(float), stream);

    dim3 grid(NBLOCKS);         // 2520 blocks, 16 live group-tasks each
    dim3 block(BLOCK);          // 256 threads = 4 waves
    ssim_kernel<<<grid, block, 0, stream>>>(X, Y, dr, acc);
    finalize_kernel<<<1, 64, 0, stream>>>(acc, out);
}